// Round 4
// baseline (157.588 us; speedup 1.0000x reference)
//
#include <hip/hip_runtime.h>
#include <math.h>

// FNO 2D spectral conv, MI355X. B=8,H=256,W=256,CIN=COUT=32,M1=M2=16.
// R6: K1 chunked staging (w-halves A/B mapping onto the existing lo/hi
// accumulator split), reg-prefetch of chunk B during compute A.
// LDS 77.8 -> 43 KB -> 3 blocks/CU (24 waves, was 16). K2/K34/K5 unchanged.

#define INV_HW (1.0f / 65536.0f)
#define STEP256 (6.28318530717958647692f / 256.0f)

// ------------------------------------------------- K1: w-DFT  x -> T
// grid 1024 = (b, h-pair), 512 thr (2 rows x 256). T layout [b][c][h][kw][2].
// chunk A: w in [0,64)+[128,192) -> folded pairs w'<64 -> lo accums
// chunk B: w in [64,128)+[192,256) -> w' in [64,128) -> hi accums
// hi fixup: T_even += (-1)^kwp * hi ; T_odd += (-1)^kwp * (-i) * hi
__global__ __launch_bounds__(512) void k_wdft(const float* __restrict__ x,
                                              float* __restrict__ T) {
  __shared__ __align__(16) float sxe[2][32 * 68];  // 17.4 KB
  __shared__ __align__(16) float sxo[2][32 * 68];  // 17.4 KB
  __shared__ __align__(16) float4 sE[512];         // [w<64][kwp] 8 KB
  int t = threadIdx.x;
  int b = blockIdx.x >> 7, h0 = (blockIdx.x & 127) << 1;
  int sub = t >> 8, tsub = t & 255;
  const float4* src =
      (const float4*)(x + ((size_t)(b * 256 + h0 + sub)) * 8192);
  // ---- chunk A loads (w 0..63 and 128..191)
  float4 av[2], bv[2];
#pragma unroll
  for (int i = 0; i < 2; ++i) {
    av[i] = src[tsub + 256 * i];          // w' = j>>3 in [0,64)
    bv[i] = src[tsub + 256 * i + 1024];   // partner w'+128
  }
  {  // twiddle gen (TRANS pipe) hidden under the loads; one entry/thread
    int w = t >> 3, kwp = t & 7;
    int me = (2 * kwp * w) & 255, mo = ((2 * kwp + 1) * w) & 255;
    float se, ce, so, co;
    sincosf(STEP256 * (float)me, &se, &ce);
    sincosf(STEP256 * (float)mo, &so, &co);
    sE[t] = make_float4(ce, -se, co, -so);
  }
  float* pe = &sxe[sub][0];
  float* po = &sxo[sub][0];
#pragma unroll
  for (int i = 0; i < 2; ++i) {
    int j = tsub + 256 * i;          // j < 512 -> w' < 64
    int w = j >> 3, c0 = (j & 7) * 4;
    float4 a = av[i], bb = bv[i];
    pe[(c0 + 0) * 68 + w] = a.x + bb.x;
    pe[(c0 + 1) * 68 + w] = a.y + bb.y;
    pe[(c0 + 2) * 68 + w] = a.z + bb.z;
    pe[(c0 + 3) * 68 + w] = a.w + bb.w;
    po[(c0 + 0) * 68 + w] = a.x - bb.x;
    po[(c0 + 1) * 68 + w] = a.y - bb.y;
    po[(c0 + 2) * 68 + w] = a.z - bb.z;
    po[(c0 + 3) * 68 + w] = a.w - bb.w;
  }
  __syncthreads();
  // ---- issue chunk B loads now; they fly during compute A
#pragma unroll
  for (int i = 0; i < 2; ++i) {
    av[i] = src[tsub + 256 * i + 512];    // w 64..127
    bv[i] = src[tsub + 256 * i + 1536];   // w 192..255
  }
  int c = (t >> 3) & 31, kwp = t & 7;
  const float* xe = pe + c * 68;
  const float* xo = po + c * 68;
  const float4* eb = sE + kwp;
  float arl = 0, ail = 0, brl = 0, bil = 0;
  float arh = 0, aih = 0, brh = 0, bih = 0;
  // ---- compute chunk A (lo accums)
#pragma unroll 4
  for (int j = 0; j < 16; ++j) {
    float4 ye = *(const float4*)(xe + 4 * j);
    float4 yo = *(const float4*)(xo + 4 * j);
    float4 e0 = eb[(4 * j + 0) * 8];
    float4 e1 = eb[(4 * j + 1) * 8];
    float4 e2 = eb[(4 * j + 2) * 8];
    float4 e3 = eb[(4 * j + 3) * 8];
    arl += ye.x * e0.x; ail += ye.x * e0.y;
    brl += yo.x * e0.z; bil += yo.x * e0.w;
    arl += ye.y * e1.x; ail += ye.y * e1.y;
    brl += yo.y * e1.z; bil += yo.y * e1.w;
    arl += ye.z * e2.x; ail += ye.z * e2.y;
    brl += yo.z * e2.z; bil += yo.z * e2.w;
    arl += ye.w * e3.x; ail += ye.w * e3.y;
    brl += yo.w * e3.z; bil += yo.w * e3.w;
  }
  __syncthreads();  // everyone done reading chunk A
  // ---- stage chunk B (same arrays)
#pragma unroll
  for (int i = 0; i < 2; ++i) {
    int j = tsub + 256 * i;
    int w = j >> 3, c0 = (j & 7) * 4;
    float4 a = av[i], bb = bv[i];
    pe[(c0 + 0) * 68 + w] = a.x + bb.x;
    pe[(c0 + 1) * 68 + w] = a.y + bb.y;
    pe[(c0 + 2) * 68 + w] = a.z + bb.z;
    pe[(c0 + 3) * 68 + w] = a.w + bb.w;
    po[(c0 + 0) * 68 + w] = a.x - bb.x;
    po[(c0 + 1) * 68 + w] = a.y - bb.y;
    po[(c0 + 2) * 68 + w] = a.z - bb.z;
    po[(c0 + 3) * 68 + w] = a.w - bb.w;
  }
  __syncthreads();
  // ---- compute chunk B (hi accums, same table w' - 64 -> fixup at end)
#pragma unroll 4
  for (int j = 0; j < 16; ++j) {
    float4 ye = *(const float4*)(xe + 4 * j);
    float4 yo = *(const float4*)(xo + 4 * j);
    float4 e0 = eb[(4 * j + 0) * 8];
    float4 e1 = eb[(4 * j + 1) * 8];
    float4 e2 = eb[(4 * j + 2) * 8];
    float4 e3 = eb[(4 * j + 3) * 8];
    arh += ye.x * e0.x; aih += ye.x * e0.y;
    brh += yo.x * e0.z; bih += yo.x * e0.w;
    arh += ye.y * e1.x; aih += ye.y * e1.y;
    brh += yo.y * e1.z; bih += yo.y * e1.w;
    arh += ye.z * e2.x; aih += ye.z * e2.y;
    brh += yo.z * e2.z; bih += yo.z * e2.w;
    arh += ye.w * e3.x; aih += ye.w * e3.y;
    brh += yo.w * e3.z; bih += yo.w * e3.w;
  }
  // T_even = lo + (-1)^kwp hi ; T_odd = lo + (-1)^kwp (-i) hi
  float sgn = (kwp & 1) ? -1.f : 1.f;
  float ar = fmaf(sgn, arh, arl);
  float ai = fmaf(sgn, aih, ail);
  float br = fmaf(sgn, bih, brl);
  float bi = fmaf(-sgn, brh, bil);
  int h = h0 + sub;
  ((float4*)(T + ((size_t)(b * 32 + c) * 256 + h) * 32))[kwp] =
      make_float4(ar, ai, br, bi);
}

// ------------------------------------------------- K2: h-DFT  T -> X
// block=(b,c) 256 x 1024 thr. Contiguous T stream; 4-way h-split + reduce.
__global__ __launch_bounds__(1024) void k_hdft(const float* __restrict__ T,
                                               float* __restrict__ X) {
  __shared__ __align__(16) float sT[8192];  // [h][kw][2] 32 KB
  __shared__ float2 sU[256];
  __shared__ float4 sRed[768];              // 12 KB
  int t = threadIdx.x;
  const float4* src = (const float4*)(T + (size_t)blockIdx.x * 8192);
  float4* dT = (float4*)sT;
  dT[t] = src[t];
  dT[t + 1024] = src[t + 1024];
  if (t < 256) {
    float s, c;
    sincosf(STEP256 * (float)t, &s, &c);
    sU[t] = make_float2(c, s);
  }
  __syncthreads();
  int kw = t & 15, kh = (t >> 4) & 15, s = t >> 8;  // s = h-quarter
  float sg = (kh & 1) ? -1.f : 1.f;  // (-1)^kha, kha parity == kh parity
  int st1 = kh, st2 = (kh + 240) & 255;
  int h0 = s * 32;
  int ph1 = (st1 * h0) & 255;
  int ph2 = (st2 * h0) & 255;
  float x0r = 0, x0i = 0, x1r = 0, x1i = 0;
#pragma unroll 4
  for (int hh = 0; hh < 32; ++hh) {
    int h = h0 + hh;
    float2 t0 = *(const float2*)(sT + h * 32 + kw * 2);
    float2 t1 = *(const float2*)(sT + (h + 128) * 32 + kw * 2);
    float tpx = fmaf(sg, t1.x, t0.x);
    float tpy = fmaf(sg, t1.y, t0.y);
    float2 e1 = sU[ph1];
    float2 e2 = sU[ph2];
    x0r += tpx * e1.x + tpy * e1.y;
    x0i += tpy * e1.x - tpx * e1.y;
    x1r += tpx * e2.x + tpy * e2.y;
    x1i += tpy * e2.x - tpx * e2.y;
    ph1 = (ph1 + st1) & 255;
    ph2 = (ph2 + st2) & 255;
  }
  if (s > 0) sRed[(s - 1) * 256 + (t & 255)] = make_float4(x0r, x0i, x1r, x1i);
  __syncthreads();
  if (s == 0) {
#pragma unroll
    for (int k = 0; k < 3; ++k) {
      float4 p = sRed[k * 256 + t];
      x0r += p.x; x0i += p.y; x1r += p.z; x1i += p.w;
    }
    float2* Xb = (float2*)(X + (size_t)blockIdx.x * 1024);
    Xb[kh * 16 + kw] = make_float2(x0r, x0i);          // kha = kh
    Xb[(kh + 16) * 16 + kw] = make_float2(x1r, x1i);   // kha = kh+240
  }
}

// ------------------------------------------------- K34: mix + h-IDFT  X -> G
// grid (b,o) = 256, 512 thr. Phase A: Y into LDS (4 KB). Phase B: h-IDFT.
__global__ __launch_bounds__(512) void k_mixidft(const float* __restrict__ X,
                                                 const float* __restrict__ wr,
                                                 const float* __restrict__ wi,
                                                 float* __restrict__ G) {
  __shared__ __align__(16) float2 sY[512];  // [row32][kw16] 4 KB
  __shared__ float2 sU[256];
  int b = blockIdx.x >> 5, o = blockIdx.x & 31;
  int t = threadIdx.x;
  if (t < 256) {
    float s, c;
    sincosf(STEP256 * (float)t, &s, &c);
    sU[t] = make_float2(c, s);
  }
  {  // phase A: channel mix, one (row,kw) per thread
    int kw = t & 15, row = t >> 4;          // row 0..31
    int blk = row >> 4, khl = row & 15;
    const float* wr0 =
        wr + (size_t)blk * 262144 + (size_t)o * 256 + khl * 16 + kw;
    const float* wi0 =
        wi + (size_t)blk * 262144 + (size_t)o * 256 + khl * 16 + kw;
    const float* Xb = X + (size_t)b * 32768 + row * 32 + kw * 2;
    float yr = 0, yi = 0;
#pragma unroll 4
    for (int i = 0; i < 32; ++i) {
      float2 xv = *(const float2*)(Xb + i * 1024);
      float a = wr0[i * 8192], bb = wi0[i * 8192];
      yr += xv.x * a - xv.y * bb;
      yi += xv.x * bb + xv.y * a;
    }
    sY[row * 16 + kw] = make_float2(yr, yi);
  }
  __syncthreads();
  // phase B: h-IDFT; even rows -> even kha (se), odd rows -> odd kha (so)
  const float4* sY4 = (const float4*)sY;
  int q = t & 7, hr = t >> 3;  // hr 0..63
#pragma unroll
  for (int hb = 0; hb < 2; ++hb) {
    int h = hr + hb * 64;  // 0..127; mirror h+128 via se-so
    float se0r = 0, se0i = 0, se1r = 0, se1i = 0;
    float so0r = 0, so0i = 0, so1r = 0, so1i = 0;
#pragma unroll 4
    for (int kh2 = 0; kh2 < 16; ++kh2) {
      int khe = 2 * kh2, kho = khe + 1;
      int khae = khe < 16 ? khe : khe + 224;
      int khao = kho < 16 ? kho : kho + 224;
      float2 ee = sU[(khae * h) & 255];
      float2 eo = sU[(khao * h) & 255];
      float4 yE = sY4[khe * 8 + q];
      float4 yO = sY4[kho * 8 + q];
      se0r += yE.x * ee.x - yE.y * ee.y;
      se0i += yE.x * ee.y + yE.y * ee.x;
      se1r += yE.z * ee.x - yE.w * ee.y;
      se1i += yE.z * ee.y + yE.w * ee.x;
      so0r += yO.x * eo.x - yO.y * eo.y;
      so0i += yO.x * eo.y + yO.y * eo.x;
      so1r += yO.z * eo.x - yO.w * eo.y;
      so1i += yO.z * eo.y + yO.w * eo.x;
    }
    float* g0 = G + (((size_t)b * 256 + h) * 32 + o) * 32 + 4 * q;
    float* g1 = G + (((size_t)b * 256 + h + 128) * 32 + o) * 32 + 4 * q;
    *(float4*)g0 =
        make_float4(se0r + so0r, se0i + so0i, se1r + so1r, se1i + so1i);
    *(float4*)g1 =
        make_float4(se0r - so0r, se0i - so0i, se1r - so1r, se1i - so1i);
  }
}

// ------------------------------------------------- K5: w-IDFT (c2r) G -> out
// E4 generated inline (TRANS) in the G-load shadow; staged in LDS (16 KB).
__global__ __launch_bounds__(256) void k_widft(const float* __restrict__ G,
                                               float* __restrict__ out) {
  __shared__ float sG[32 * 33];
  __shared__ __align__(16) float4 sE4[1024];  // [w<128][q] 16 KB
  int bh = blockIdx.x, t = threadIdx.x;
  float4 v = ((const float4*)(G + (size_t)bh * 1024))[t];
#pragma unroll
  for (int r = 0; r < 4; ++r) {  // twiddle gen hidden under the G load
    int i = t + 256 * r;
    int w = i >> 3, q = i & 7;
    int me = (2 * q * w) & 255, mo = ((2 * q + 1) * w) & 255;
    float se, ce, so, co;
    sincosf(STEP256 * (float)me, &se, &ce);
    sincosf(STEP256 * (float)mo, &so, &co);
    float sc_e = (q == 0) ? INV_HW : 2.0f * INV_HW;
    sE4[i] = make_float4(sc_e * ce, sc_e * se, 2.0f * INV_HW * co,
                         2.0f * INV_HW * so);
  }
  {
    int o = t >> 3, p = t & 7;
    float* d = sG + o * 33 + p * 4;
    d[0] = v.x; d[1] = v.y; d[2] = v.z; d[3] = v.w;
  }
  __syncthreads();
  int o = t & 31, wb = t >> 5;
  float g[32];
#pragma unroll
  for (int k = 0; k < 32; ++k) g[k] = sG[o * 33 + k];
  float* ob = out + (size_t)bh * 8192 + o;
#pragma unroll 2
  for (int j = 0; j < 16; ++j) {
    int w = wb * 16 + j;
    float se = 0.f, so = 0.f;
#pragma unroll
    for (int q = 0; q < 8; ++q) {
      float4 e = sE4[w * 8 + q];
      se += g[4 * q] * e.x - g[4 * q + 1] * e.y;
      so += g[4 * q + 2] * e.z - g[4 * q + 3] * e.w;
    }
    ob[(size_t)w * 32] = se + so;
    ob[(size_t)(w + 128) * 32] = se - so;
  }
}

extern "C" void kernel_launch(void* const* d_in, const int* in_sizes, int n_in,
                              void* d_out, int out_size, void* d_ws,
                              size_t ws_size, hipStream_t stream) {
  const float* x = (const float*)d_in[0];   // [8,256,256,32]
  const float* wr = (const float*)d_in[1];  // [2,32,32,16,16]
  const float* wi = (const float*)d_in[2];
  float* out = (float*)d_out;               // [8,256,256,32]
  float* ws = (float*)d_ws;

  float* T = ws;            // 2097152 f  [b][c][h][kw][2]
  float* X = ws + 2097152;  // 262144 f   [b*32+c][row][kw][2]
  float* G = T;             // reuse (T dead after K2)

  k_wdft<<<1024, 512, 0, stream>>>(x, T);
  k_hdft<<<256, 1024, 0, stream>>>(T, X);
  k_mixidft<<<256, 512, 0, stream>>>(X, wr, wi, G);
  k_widft<<<2048, 256, 0, stream>>>(G, out);
}